// Round 6
// baseline (557.800 us; speedup 1.0000x reference)
//
#include <hip/hip_runtime.h>
#include <hip/hip_cooperative_groups.h>
#include <math.h>
#include <stdint.h>

namespace cg = cooperative_groups;

#define NROWS 4096
#define CDIM 1024
#define T0_LO 2000
#define T0_HI 10000
#define T1_LO 10000
#define ROOT_COLS 2002
#define ROOT_PAD 2048
#define T0_COLS 8000
#define T0_PAD 8064
#define T1_COLS 40257
#define T1_PAD 40320
#define HB_STRIDE 320
#define LOG2E 1.44269504088896340736f
#define LN2 0.69314718055994530942f
#define GRID 512

using short8  = __attribute__((ext_vector_type(8))) short;
using ushort8 = __attribute__((ext_vector_type(8))) unsigned short;
using floatx4 = __attribute__((ext_vector_type(4))) float;

__device__ __forceinline__ unsigned short f2bf(float x) {
  union { float f; unsigned int u; } v; v.f = x;
  unsigned int r = v.u + 0x7fffu + ((v.u >> 16) & 1u);
  return (unsigned short)(r >> 16);
}
__device__ __forceinline__ float bf2f(unsigned short h) {
  union { unsigned int u; float f; } v; v.u = ((unsigned int)h) << 16;
  return v.f;
}
__device__ __forceinline__ floatx4 mfma16(short8 a, short8 b, floatx4 c) {
  return __builtin_amdgcn_mfma_f32_16x16x32_bf16(a, b, c, 0, 0, 0);
}
// Async global->LDS 16B: lane i's data lands at lds_wave_base + i*16.
__device__ __forceinline__ void stage16(const unsigned short* g,
                                        unsigned short* lds_wave_base, int lane) {
#if __has_builtin(__builtin_amdgcn_global_load_lds)
  __builtin_amdgcn_global_load_lds(
      (const __attribute__((address_space(1))) void*)g,
      (__attribute__((address_space(3))) void*)lds_wave_base, 16, 0, 0);
#else
  ((ushort8*)lds_wave_base)[lane] = *(const ushort8*)g;
#endif
}

// ---------------- workspace layout (bytes) ----------------
static constexpr size_t B_HB  = 0;                          // ushort[4096*320]
static constexpr size_t B_LB  = B_HB + 4096ull * 320 * 2;   // ushort[4096*1024] bf16 logits
static constexpr size_t B_WP  = B_LB + 4096ull * 1024 * 2;  // ushort[384*1024] (rows 320..383 zero)
static constexpr size_t B_WH  = B_WP + 384ull * 1024 * 2;   // ushort[2048*1024]  (x log2e)
static constexpr size_t B_WS0 = B_WH + 2048ull * 1024 * 2;  // ushort[8064*256]   (x log2e, pad 64)
static constexpr size_t B_WS1 = B_WS0 + 8064ull * 256 * 2;  // ushort[40320*64]   (x log2e, pad 63)
static constexpr size_t B_S   = B_WS1 + 40320ull * 64 * 2;  // float[3*4096]
static constexpr size_t B_P   = B_S + 3ull * 4096 * 4;      // float[3*4096]
static constexpr size_t B_I0  = B_P + 3ull * 4096 * 4;
static constexpr size_t B_I1  = B_I0 + 4096ull * 4;
static constexpr size_t B_CNT = B_I1 + 4096ull * 4;

// 32x32 f32 tile transpose -> bf16 (x scale). r19-verified (tid<128 guard,
// alignment-tiered loads: N%4==0 float4 / N%2==0 float2 / scalar).
__device__ __forceinline__ void transpose_tile(
    const float* __restrict__ W, unsigned short* __restrict__ Wt,
    int K, int N, int Npad, int nx, int rel, float scale,
    float (*tile)[33], int tid) {
  const int n0 = (rel % nx) * 32, k0 = (rel / nx) * 32;
  if ((N & 3) == 0) {          // float4 path: scale0, proj0, proj1
    const int lk = tid >> 3, ln = (tid & 7) << 2;
    const int n = n0 + ln;
    float4 v = make_float4(0.f, 0.f, 0.f, 0.f);
    if (n + 3 < N) v = *(const float4*)(W + (size_t)(k0 + lk) * N + n);
    tile[lk][ln]     = v.x * scale;
    tile[lk][ln + 1] = v.y * scale;
    tile[lk][ln + 2] = v.z * scale;
    tile[lk][ln + 3] = v.w * scale;
  } else if ((N & 1) == 0) {   // float2 path: head (N=2002)
    const int lk = tid >> 4, ln = (tid & 15) << 1;
#pragma unroll
    for (int i = 0; i < 32; i += 16) {
      const int n = n0 + ln;
      float2 v = make_float2(0.f, 0.f);
      if (n + 1 < N) v = *(const float2*)(W + (size_t)(k0 + lk + i) * N + n);
      tile[lk + i][ln]     = v.x * scale;
      tile[lk + i][ln + 1] = v.y * scale;
    }
  } else {                     // scalar path: scale1 (N odd)
    const int tx = tid & 31, ty = tid >> 5;
    for (int i = 0; i < 32; i += 8) {
      int k = k0 + ty + i, n = n0 + tx;
      tile[ty + i][tx] = (n < N) ? W[(size_t)k * N + n] * scale : 0.f;
    }
  }
  __syncthreads();
  // write: 32 n-rows x 4 ushort8 (16 B) stores = 128 threads
  if (tid < 128) {
    const int nloc = tid >> 2, kg = tid & 3;
    const int n = n0 + nloc;
    if (n < Npad) {
      ushort8 x;
#pragma unroll
      for (int j = 0; j < 8; j++) x[j] = f2bf(tile[kg * 8 + j][nloc]);
      *(ushort8*)&Wt[(size_t)n * K + k0 + kg * 8] = x;
    }
  }
}

// ---------------- prep virtual blocks --------------------------------------
#define PP_WH_END   2048                     // head: 64 x 32 tiles
#define PP_WS0_END  (PP_WH_END + 2016)       // scale0: 252 x 8
#define PP_WS1_END  (PP_WS0_END + 2520)      // scale1: 1260 x 2
#define PP_WP0_END  (PP_WS1_END + 256)       // proj0: 8 x 32
#define PP_WP1_END  (PP_WP0_END + 64)        // proj1: 2 x 32
#define PP_LB_END   (PP_WP1_END + 2048)      // logits cast
#define PP_ZERO_END (PP_LB_END + 32)         // Wp rows 320..383
#define PP_S_END    (PP_ZERO_END + 4)        // S zero
#define PP_TOTAL    (PP_S_END + 1)           // compact (single virtual block)

__device__ __forceinline__ void prep_block(
    int id, int tid, unsigned char* smem,
    const float* __restrict__ head, const float* __restrict__ proj0,
    const float* __restrict__ proj1, const float* __restrict__ scale0,
    const float* __restrict__ scale1, const float* __restrict__ logits,
    const int* __restrict__ targets,
    unsigned short* __restrict__ Wh, unsigned short* __restrict__ Wp,
    unsigned short* __restrict__ Ws0, unsigned short* __restrict__ Ws1,
    unsigned short* __restrict__ Lb, float* __restrict__ S,
    int* __restrict__ idx0, int* __restrict__ idx1, int* __restrict__ cnt) {
  float (*tile)[33] = (float(*)[33])smem;
  if (id < PP_WP1_END) {  // weight transposes
    const float* W; unsigned short* Wt; int K, N, Npad, nx, rel; float scale;
    if (id < PP_WH_END)        { W = head;   Wt = Wh;  K = 1024; N = ROOT_COLS; Npad = ROOT_PAD; scale = LOG2E; nx = 64;   rel = id; }
    else if (id < PP_WS0_END)  { W = scale0; Wt = Ws0; K = 256;  N = T0_COLS;   Npad = T0_PAD;   scale = LOG2E; nx = 252;  rel = id - PP_WH_END; }
    else if (id < PP_WS1_END)  { W = scale1; Wt = Ws1; K = 64;   N = T1_COLS;   Npad = T1_PAD;   scale = LOG2E; nx = 1260; rel = id - PP_WS0_END; }
    else if (id < PP_WP0_END)  { W = proj0;  Wt = Wp;  K = 1024; N = 256;       Npad = 256;      scale = 1.f;   nx = 8;    rel = id - PP_WS1_END; }
    else                       { W = proj1;  Wt = Wp + 256 * 1024; K = 1024; N = 64; Npad = 64; scale = 1.f; nx = 2; rel = id - PP_WP0_END; }
    transpose_tile(W, Wt, K, N, Npad, nx, rel, scale, tile, tid);
    return;
  }
  if (id < PP_LB_END) {  // logits f32 -> bf16, 2048 elements/block
    size_t base = (size_t)(id - PP_WP1_END) * 2048 + tid * 8;
    float4 v0 = *(const float4*)(logits + base);
    float4 v1 = *(const float4*)(logits + base + 4);
    ushort8 h;
    h[0] = f2bf(v0.x); h[1] = f2bf(v0.y); h[2] = f2bf(v0.z); h[3] = f2bf(v0.w);
    h[4] = f2bf(v1.x); h[5] = f2bf(v1.y); h[6] = f2bf(v1.z); h[7] = f2bf(v1.w);
    *(ushort8*)(Lb + base) = h;
    return;
  }
  if (id < PP_ZERO_END) {  // zero Wp rows 320..383
    size_t off = (size_t)(id - PP_LB_END) * 2048 + tid * 8;
    ushort8 z = {0, 0, 0, 0, 0, 0, 0, 0};
    *(ushort8*)(Wp + 320ull * 1024 + off) = z;
    return;
  }
  if (id < PP_S_END) {  // zero S (12288 floats over 4 virtual blocks)
    int rel = id - PP_ZERO_END;
    float4 z = make_float4(0.f, 0.f, 0.f, 0.f);
#pragma unroll
    for (int j = 0; j < 3; j++)
      ((float4*)S)[rel * 768 + j * 256 + tid] = z;
    return;
  }
  // compact: one virtual block, LDS counters
  int* base2 = (int*)smem;
  if (tid < 2) base2[tid] = 0;
  __syncthreads();
  for (int n = tid; n < NROWS; n += 256) {
    int t = targets[n];
    if (t >= T0_LO && t < T0_HI) idx0[atomicAdd(&base2[0], 1)] = n;
    else if (t >= T1_LO)         idx1[atomicAdd(&base2[1], 1)] = n;
  }
  __syncthreads();
  if (tid < 2) cnt[tid] = base2[tid];
}

// Shared 64-row x CI-cg x K=1024 MFMA K-loop (double-buffered KC=128 halves).
template<int CI>
__device__ __forceinline__ void gemm64_kloop(
    unsigned short* A_lds,   // 2 x (64*128) ushorts = 32 KB
    const unsigned short* Arow,
    const unsigned short* const (&Bbase)[CI],
    floatx4 (&acc)[CI][4], int tid) {
  const int lane = tid & 63, w = tid >> 6;
  const int m = lane & 15, quad = lane >> 4, keym = m & 7;
  int goff[4];
#pragma unroll
  for (int it = 0; it < 4; it++) {
    int s = w * 256 + it * 64 + lane;
    int r = s >> 4, p = s & 15;
    int cq = p ^ (r & 7);
    goff[it] = r * CDIM + cq * 8;
  }
#pragma unroll
  for (int it = 0; it < 4; it++)
    stage16(Arow + goff[it], &A_lds[(w * 256 + it * 64) * 8], lane);
  for (int h = 0; h < 8; h++) {
    unsigned short* cur = A_lds + (h & 1) * (64 * 128);
    unsigned short* nxt = A_lds + ((h + 1) & 1) * (64 * 128);
    __syncthreads();
    if (h + 1 < 8) {
#pragma unroll
      for (int it = 0; it < 4; it++)
        stage16(Arow + goff[it] + (h + 1) * 128,
                &nxt[(w * 256 + it * 64) * 8], lane);
    }
    short8 b[CI][4];
#pragma unroll
    for (int ci = 0; ci < CI; ci++)
#pragma unroll
      for (int ks = 0; ks < 4; ks++)
        b[ci][ks] = *(const short8*)(Bbase[ci] + h * 128 + ks * 32);
    short8 areg[4][4];
#pragma unroll
    for (int t = 0; t < 4; t++)
#pragma unroll
      for (int ks = 0; ks < 4; ks++) {
        int ch = ((ks << 2) + quad) ^ keym;
        areg[t][ks] = *(const short8*)&cur[(t * 16 + m) * 128 + (ch << 3)];
      }
#pragma unroll
    for (int ci = 0; ci < CI; ci++)
#pragma unroll
      for (int ks = 0; ks < 4; ks++)
#pragma unroll
        for (int t = 0; t < 4; t++)
          acc[ci][t] = mfma16(areg[t][ks], b[ci][ks], acc[ci][t]);
  }
}

// ---------------- hidden virtual block (320 works) --------------------------
__device__ __forceinline__ void hidden_block(
    int id, int tid, unsigned char* smem,
    const unsigned short* __restrict__ Lb,
    const unsigned short* __restrict__ Wp,
    unsigned short* __restrict__ Hb) {
  unsigned short* A_lds = (unsigned short*)smem;  // 32 KB
  const int xcd = id & 7, k = id >> 3;            // k in [0,40)
  const int row0 = (xcd * 8 + (k & 7)) * 64;
  const int cg0 = k >> 3;                         // [0,5)
  const int lane = tid & 63, w = tid >> 6;
  const int m = lane & 15, quad = lane >> 4;
  const floatx4 zf = {0.f, 0.f, 0.f, 0.f};
  floatx4 acc[1][4];
#pragma unroll
  for (int t = 0; t < 4; t++) acc[0][t] = zf;
  const unsigned short* Bb[1] = {
      Wp + (size_t)(cg0 * 64 + w * 16 + m) * CDIM + quad * 8};
  gemm64_kloop<1>(A_lds, Lb + (size_t)row0 * CDIM, Bb, acc, tid);
  int n = cg0 * 64 + w * 16 + m;
  if (n < HB_STRIDE) {
#pragma unroll
    for (int t = 0; t < 4; t++)
#pragma unroll
      for (int r = 0; r < 4; r++)
        Hb[(size_t)(row0 + t * 16 + quad * 4 + r) * HB_STRIDE + n] =
            f2bf(acc[0][t][r]);
  }
}

// ---------------- mega virtual blocks (r1 structure, proven) ----------------
#define MG_ROOT 512           // 32 x-tiles (BM=128) x 16 cg-pairs
#define MG_T1   480           // 32 row-tiles (BM=128) x 15 y
#define MG_T0   2688          // 128 row-tiles x 21 y
#define MG_PICK 1024
#define MG_TOTAL (MG_ROOT + MG_T1 + MG_T0 + MG_PICK)

__device__ __forceinline__ void root_compute(
    const unsigned short* cur, const short8 (&b)[2][2], floatx4 (&acc)[2][8],
    int m, int quad, int keym) {
#pragma unroll
  for (int hf = 0; hf < 2; hf++) {
    short8 areg[4][2];
#pragma unroll
    for (int t = 0; t < 4; t++)
#pragma unroll
      for (int ks = 0; ks < 2; ks++) {
        int ch = ((ks << 2) + quad) ^ keym;
        areg[t][ks] = *(const short8*)&cur[(hf * 64 + t * 16 + m) * 64 + (ch << 3)];
      }
#pragma unroll
    for (int ci = 0; ci < 2; ci++)
#pragma unroll
      for (int ks = 0; ks < 2; ks++)
#pragma unroll
        for (int t = 0; t < 4; t++)
          acc[ci][hf * 4 + t] = mfma16(areg[t][ks], b[ci][ks], acc[ci][hf * 4 + t]);
  }
}

__device__ __forceinline__ void root_stage(
    const unsigned short* Arow, const int (&goff)[4], int koff,
    unsigned short* buf, int w, int lane) {
#pragma unroll
  for (int it = 0; it < 4; it++)
    stage16(Arow + goff[it] + koff, &buf[(it * 256 + w * 64) * 8], lane);
}

__device__ __forceinline__ void root_loadB(
    const unsigned short* const (&Bb)[2], int koff, short8 (&b)[2][2]) {
#pragma unroll
  for (int ci = 0; ci < 2; ci++)
#pragma unroll
    for (int ks = 0; ks < 2; ks++)
      b[ci][ks] = *(const short8*)(Bb[ci] + koff + ks * 32);
}

__device__ __forceinline__ void root_path(
    unsigned char* smem, int bx, int by,
    const unsigned short* __restrict__ Lb,
    const unsigned short* __restrict__ Wh, float* __restrict__ S) {
  unsigned short* bufA = (unsigned short*)smem;   // 128 rows x 64 k = 16 KB
  unsigned short* bufB = bufA + 128 * 64;         // second half
  const int tid = threadIdx.x;
  const int row0 = bx * 128;
  const int cg0 = by * 2;
  const int lane = tid & 63, w = tid >> 6;
  const int m = lane & 15, quad = lane >> 4, keym = m & 7;
  const floatx4 zf = {0.f, 0.f, 0.f, 0.f};
  floatx4 acc[2][8];
#pragma unroll
  for (int ci = 0; ci < 2; ci++)
#pragma unroll
    for (int t = 0; t < 8; t++) acc[ci][t] = zf;
  const unsigned short* Bb[2] = {
      Wh + (size_t)((cg0 + 0) * 64 + w * 16 + m) * CDIM + quad * 8,
      Wh + (size_t)((cg0 + 1) * 64 + w * 16 + m) * CDIM + quad * 8};
  const unsigned short* Arow = Lb + (size_t)row0 * CDIM;
  int goff[4];
#pragma unroll
  for (int it = 0; it < 4; it++) {
    int s = it * 256 + w * 64 + lane;
    int r = s >> 3, p = s & 7;
    int cq = p ^ (r & 7);
    goff[it] = r * CDIM + cq * 8;
  }
  short8 b0[2][2], b1[2][2];
  root_stage(Arow, goff, 0, bufA, w, lane);   // chunk 0 in flight
  root_loadB(Bb, 0, b0);
  for (int hh = 0; hh < 8; hh++) {
    __syncthreads();                          // drains chunk 2hh into bufA
    root_stage(Arow, goff, (hh * 2 + 1) * 64, bufB, w, lane);
    root_loadB(Bb, (hh * 2 + 1) * 64, b1);
    root_compute(bufA, b0, acc, m, quad, keym);
    __syncthreads();                          // drains chunk 2hh+1 into bufB
    if (hh < 7) {
      root_stage(Arow, goff, (hh * 2 + 2) * 64, bufA, w, lane);
      root_loadB(Bb, (hh * 2 + 2) * 64, b0);
    }
    root_compute(bufB, b1, acc, m, quad, keym);
  }
  // epilogue: reuse smem for 128 per-row sums
  __syncthreads();
  float* sums = (float*)smem;
  if (tid < 128) sums[tid] = 0.f;
  __syncthreads();
#pragma unroll
  for (int t = 0; t < 8; t++)
#pragma unroll
    for (int r = 0; r < 4; r++) {
      float e = __builtin_amdgcn_exp2f(acc[0][t][r]) +
                __builtin_amdgcn_exp2f(acc[1][t][r]);
      e += __shfl_xor(e, 1); e += __shfl_xor(e, 2);
      e += __shfl_xor(e, 4); e += __shfl_xor(e, 8);
      if (m == 0)
        atomicAdd(&sums[(t >> 2) * 64 + (t & 3) * 16 + quad * 4 + r], e);
    }
  __syncthreads();
  if (tid < 128) atomicAdd(&S[row0 + tid], sums[tid]);
}

template<int K, int TILES, int MODE>
__device__ __forceinline__ void tail_path(
    unsigned char* smem, int bx, int by,
    const unsigned short* __restrict__ Hb, int acol0,
    const unsigned short* __restrict__ Wt, int ncgpb,
    const int* __restrict__ idx, const int* __restrict__ cnt,
    float* __restrict__ S) {
  constexpr int BM = TILES * 16;
  constexpr int CpR = K / 8;
  constexpr int KS = K / 32;
  unsigned short* A_lds = (unsigned short*)smem;            // BM*K ushorts
  int* row_lds = (int*)(smem + (size_t)BM * K * 2);
  float* sum_lds = (float*)(smem + (size_t)BM * K * 2 + BM * 4);
  const int tid = threadIdx.x;
  const int count = cnt[MODE - 1];
  const int row0 = bx * BM;
  if (row0 >= count) return;
  if (tid < BM) {
    int r = row0 + tid;
    row_lds[tid] = (r < count) ? idx[r] : -1;
    sum_lds[tid] = 0.f;
  }
  __syncthreads();
#pragma unroll
  for (int i = 0; i < BM * CpR / 256; i++) {
    int c = tid + 256 * i;
    int rl = c / CpR, cq = c % CpR;
    int row = row_lds[rl];
    ushort8 v = {0, 0, 0, 0, 0, 0, 0, 0};
    if (row >= 0) v = *(const ushort8*)(Hb + (size_t)row * HB_STRIDE + acol0 + cq * 8);
    *(ushort8*)&A_lds[rl * K + ((cq ^ (rl & 7)) << 3)] = v;
  }
  __syncthreads();
  const int lane = tid & 63, w = tid >> 6;
  const int m = lane & 15, quad = lane >> 4, keym = m & 7;
  const floatx4 zf = {0.f, 0.f, 0.f, 0.f};
  short8 areg[TILES][KS];
#pragma unroll
  for (int t = 0; t < TILES; t++)
#pragma unroll
    for (int ks = 0; ks < KS; ks++) {
      int ch = ((ks << 2) + quad) ^ keym;
      areg[t][ks] = *(const short8*)&A_lds[(t * 16 + m) * K + (ch << 3)];
    }
  float runsum[TILES][4];
#pragma unroll
  for (int t = 0; t < TILES; t++)
#pragma unroll
    for (int r = 0; r < 4; r++) runsum[t][r] = 0.f;

  const int cg0 = by * ncgpb;
  const unsigned short* Bp = Wt + (size_t)(cg0 * 64 + w * 16 + m) * K + quad * 8;
  short8 b0[KS], b1[KS];
#pragma unroll
  for (int ks = 0; ks < KS; ks++) b0[ks] = *(const short8*)(Bp + ks * 32);
#pragma unroll
  for (int ks = 0; ks < KS; ks++)
    b1[ks] = *(const short8*)(Bp + (size_t)64 * K + ks * 32);

  for (int cc = 0; cc < ncgpb; cc += 2) {  // runtime loop, literal reg indices
    floatx4 acc[TILES];
#pragma unroll
    for (int t = 0; t < TILES; t++) acc[t] = zf;
#pragma unroll
    for (int ks = 0; ks < KS; ks++)
#pragma unroll
      for (int t = 0; t < TILES; t++) acc[t] = mfma16(areg[t][ks], b0[ks], acc[t]);
    if (cc + 2 < ncgpb) {
      const unsigned short* p = Bp + (size_t)(cc + 2) * 64 * K;
#pragma unroll
      for (int ks = 0; ks < KS; ks++) b0[ks] = *(const short8*)(p + ks * 32);
    }
#pragma unroll
    for (int t = 0; t < TILES; t++)
#pragma unroll
      for (int r = 0; r < 4; r++)
        runsum[t][r] += __builtin_amdgcn_exp2f(acc[t][r]);

#pragma unroll
    for (int t = 0; t < TILES; t++) acc[t] = zf;
#pragma unroll
    for (int ks = 0; ks < KS; ks++)
#pragma unroll
      for (int t = 0; t < TILES; t++) acc[t] = mfma16(areg[t][ks], b1[ks], acc[t]);
    if (cc + 3 < ncgpb) {
      const unsigned short* p = Bp + (size_t)(cc + 3) * 64 * K;
#pragma unroll
      for (int ks = 0; ks < KS; ks++) b1[ks] = *(const short8*)(p + ks * 32);
    }
#pragma unroll
    for (int t = 0; t < TILES; t++)
#pragma unroll
      for (int r = 0; r < 4; r++)
        runsum[t][r] += __builtin_amdgcn_exp2f(acc[t][r]);
  }

#pragma unroll
  for (int t = 0; t < TILES; t++)
#pragma unroll
    for (int r = 0; r < 4; r++) {
      float e = runsum[t][r];
      e += __shfl_xor(e, 1); e += __shfl_xor(e, 2);
      e += __shfl_xor(e, 4); e += __shfl_xor(e, 8);
      if (m == 0) atomicAdd(&sum_lds[t * 16 + quad * 4 + r], e);
    }
  __syncthreads();
  if (tid < BM) {
    int row = row_lds[tid];
    if (row >= 0) atomicAdd(&S[row], sum_lds[tid]);
  }
}

__device__ __forceinline__ void picked_path(
    int rel, const float* __restrict__ logits, const int* __restrict__ targets,
    const unsigned short* __restrict__ Wh,
    const unsigned short* __restrict__ Ws0,
    const unsigned short* __restrict__ Ws1,
    const unsigned short* __restrict__ Hb, float* __restrict__ P) {
  const int tid = threadIdx.x, lane = tid & 63;
  const int row = rel * 4 + (tid >> 6);
  const int t = targets[row];
  const int tr = (t >= T0_LO && t < T0_HI) ? T0_LO : ((t >= T1_LO) ? T0_LO + 1 : t);
  const float* a = logits + (size_t)row * CDIM + lane * 16;
  const unsigned short* wr = Wh + (size_t)tr * CDIM + lane * 16;
  float acc = 0.f;
#pragma unroll
  for (int q = 0; q < 2; q++) {
    ushort8 wv = *(const ushort8*)(wr + q * 8);
    float4 a0 = ((const float4*)a)[q * 2];
    float4 a1 = ((const float4*)a)[q * 2 + 1];
    acc += a0.x * bf2f(wv[0]) + a0.y * bf2f(wv[1]) + a0.z * bf2f(wv[2]) + a0.w * bf2f(wv[3]);
    acc += a1.x * bf2f(wv[4]) + a1.y * bf2f(wv[5]) + a1.z * bf2f(wv[6]) + a1.w * bf2f(wv[7]);
  }
#pragma unroll
  for (int off = 1; off < 64; off <<= 1) acc += __shfl_xor(acc, off);
  if (lane == 0) P[row] = acc * LN2;
  if (t >= T0_LO) {
    float acc2 = 0.f;
    if (t < T0_HI) {
      const unsigned short* h = Hb + (size_t)row * HB_STRIDE + lane * 4;
      const unsigned short* w2 = Ws0 + (size_t)(t - T0_LO) * 256 + lane * 4;
#pragma unroll
      for (int j = 0; j < 4; j++) acc2 += bf2f(h[j]) * bf2f(w2[j]);
    } else {
      acc2 = bf2f(Hb[(size_t)row * HB_STRIDE + 256 + lane]) *
             bf2f(Ws1[(size_t)(t - T1_LO) * 64 + lane]);
    }
#pragma unroll
    for (int off = 1; off < 64; off <<= 1) acc2 += __shfl_xor(acc2, off);
    if (lane == 0) P[(t < T0_HI ? NROWS : 2 * NROWS) + row] = acc2 * LN2;
  }
}

__device__ __forceinline__ void mega_block(
    int bid, unsigned char* smem,
    const unsigned short* __restrict__ Lb,
    const unsigned short* __restrict__ Wh,
    const unsigned short* __restrict__ Ws0,
    const unsigned short* __restrict__ Ws1,
    const unsigned short* __restrict__ Hb,
    const float* __restrict__ logits, const int* __restrict__ targets,
    const int* __restrict__ idx0, const int* __restrict__ idx1,
    const int* __restrict__ cnt, float* __restrict__ S, float* __restrict__ P) {
  if (bid < MG_ROOT) {
    int wk = ((bid & 7) << 6) + (bid >> 3);      // [0,512) bijective
    root_path(smem, wk >> 4, wk & 15, Lb, Wh, S);
    return;
  }
  bid -= MG_ROOT;
  if (bid < MG_T1) {
    int wk = (bid & 7) * 60 + (bid >> 3);        // [0,480) bijective
    tail_path<64, 8, 2>(smem, wk & 31, wk >> 5, Hb, 256, Ws1, 42, idx1, cnt,
                        S + 2 * NROWS);
    return;
  }
  bid -= MG_T1;
  if (bid < MG_T0) {
    int wk = (bid & 7) * 336 + (bid >> 3);       // [0,2688) bijective
    tail_path<256, 2, 1>(smem, wk & 127, wk >> 7, Hb, 0, Ws0, 6, idx0, cnt,
                         S + NROWS);
    return;
  }
  bid -= MG_T0;
  picked_path(bid, logits, targets, Wh, Ws0, Ws1, Hb, P);
}

__device__ __forceinline__ void loss_block(
    int tid, unsigned char* smem, const int* __restrict__ targets,
    const float* __restrict__ S, const float* __restrict__ P,
    float* __restrict__ out) {
  float sr = 0.f, s0 = 0.f, s1 = 0.f, c0 = 0.f, c1 = 0.f;
  for (int n = tid; n < NROWS; n += 256) {
    int t = targets[n];
    sr += logf(S[n] - 46.f) - P[n];  // 46 root pad cols -> exp2(0)=1 each
    if (t >= T0_LO && t < T0_HI) { s0 += logf(S[NROWS + n] - 64.f) - P[NROWS + n]; c0 += 1.f; }
    else if (t >= T1_LO)         { s1 += logf(S[2 * NROWS + n] - 63.f) - P[2 * NROWS + n]; c1 += 1.f; }
  }
  for (int off = 32; off > 0; off >>= 1) {
    sr += __shfl_down(sr, off);
    s0 += __shfl_down(s0, off);
    s1 += __shfl_down(s1, off);
    c0 += __shfl_down(c0, off);
    c1 += __shfl_down(c1, off);
  }
  float (*red)[5] = (float(*)[5])smem;
  int wv = tid >> 6;
  if ((tid & 63) == 0) { red[wv][0] = sr; red[wv][1] = s0; red[wv][2] = s1; red[wv][3] = c0; red[wv][4] = c1; }
  __syncthreads();
  if (tid == 0) {
    sr = 0.f; s0 = 0.f; s1 = 0.f; c0 = 0.f; c1 = 0.f;
#pragma unroll
    for (int i = 0; i < 4; i++) {
      sr += red[i][0]; s0 += red[i][1]; s1 += red[i][2];
      c0 += red[i][3]; c1 += red[i][4];
    }
    float root_loss = sr / (float)NROWS;
    float l0 = s0 / fmaxf(c0, 1.f);
    float l1 = s1 / fmaxf(c1, 1.f);
    out[0] = (root_loss + l0 + l1) / 3.f;
  }
}

// ---------------- uber kernel: single cooperative launch --------------------
// r20: non-mega time invariant at ~107 us across 4 prep restructures while
// work-arithmetic says ~35 us -> the fixed cost is the 4-launch structure
// (gaps + 13.7k workgroup dispatches). One cooperative launch, 512 persistent
// blocks (2/CU guaranteed by bounds+32KB LDS), grid.sync() between phases.
__global__ __launch_bounds__(256, 2) void uber_kernel(
    const float* __restrict__ logits, const int* __restrict__ targets,
    const float* __restrict__ head, const float* __restrict__ proj0,
    const float* __restrict__ scale0, const float* __restrict__ proj1,
    const float* __restrict__ scale1, char* __restrict__ ws,
    float* __restrict__ out) {
  __shared__ __align__(16) unsigned char smem[32768];
  unsigned short* Hb  = (unsigned short*)(ws + B_HB);
  unsigned short* Lb  = (unsigned short*)(ws + B_LB);
  unsigned short* Wp  = (unsigned short*)(ws + B_WP);
  unsigned short* Wh  = (unsigned short*)(ws + B_WH);
  unsigned short* Ws0 = (unsigned short*)(ws + B_WS0);
  unsigned short* Ws1 = (unsigned short*)(ws + B_WS1);
  float* S = (float*)(ws + B_S);
  float* P = (float*)(ws + B_P);
  int* idx0 = (int*)(ws + B_I0);
  int* idx1 = (int*)(ws + B_I1);
  int* cnt  = (int*)(ws + B_CNT);
  const int bid = blockIdx.x, tid = threadIdx.x;

  // phase 1: prep (transposes + cast + zeros + compact)
  for (int vb = bid; vb < PP_TOTAL; vb += GRID) {
    prep_block(vb, tid, smem, head, proj0, proj1, scale0, scale1, logits,
               targets, Wh, Wp, Ws0, Ws1, Lb, S, idx0, idx1, cnt);
    __syncthreads();  // LDS WAR between virtual blocks
  }
  __threadfence();
  cg::this_grid().sync();

  // phase 2: hidden (320 works; <=1 per block, no loop-sync needed)
  for (int vb = bid; vb < 320; vb += GRID)
    hidden_block(vb, tid, smem, Lb, Wp, Hb);
  __threadfence();
  cg::this_grid().sync();

  // phase 3: mega (root 512 lands exactly on stride-iteration 0)
  for (int vb = bid; vb < MG_TOTAL; vb += GRID) {
    mega_block(vb, smem, Lb, Wh, Ws0, Ws1, Hb, logits, targets, idx0, idx1,
               cnt, S, P);
    __syncthreads();  // LDS WAR between virtual blocks
  }
  __threadfence();
  cg::this_grid().sync();

  // phase 4: loss
  if (bid == 0) loss_block(tid, smem, targets, S, P, out);
}

// ---------------- fallback wrappers (if cooperative launch unavailable) -----
__global__ __launch_bounds__(256) void prep_kernel_g(
    const float* __restrict__ head, const float* __restrict__ proj0,
    const float* __restrict__ proj1, const float* __restrict__ scale0,
    const float* __restrict__ scale1, const float* __restrict__ logits,
    const int* __restrict__ targets,
    unsigned short* __restrict__ Wh, unsigned short* __restrict__ Wp,
    unsigned short* __restrict__ Ws0, unsigned short* __restrict__ Ws1,
    unsigned short* __restrict__ Lb, float* __restrict__ S,
    int* __restrict__ idx0, int* __restrict__ idx1, int* __restrict__ cnt) {
  __shared__ __align__(16) unsigned char smem[4352];
  prep_block(blockIdx.x, threadIdx.x, smem, head, proj0, proj1, scale0, scale1,
             logits, targets, Wh, Wp, Ws0, Ws1, Lb, S, idx0, idx1, cnt);
}

__global__ __launch_bounds__(256) void hidden_kernel_g(
    const unsigned short* __restrict__ Lb, const unsigned short* __restrict__ Wp,
    unsigned short* __restrict__ Hb) {
  __shared__ __align__(16) unsigned char smem[32768];
  hidden_block(blockIdx.x, threadIdx.x, smem, Lb, Wp, Hb);
}

__global__ __launch_bounds__(256, 2) void mega_kernel_g(
    const unsigned short* __restrict__ Lb,
    const unsigned short* __restrict__ Wh,
    const unsigned short* __restrict__ Ws0,
    const unsigned short* __restrict__ Ws1,
    const unsigned short* __restrict__ Hb,
    const float* __restrict__ logits, const int* __restrict__ targets,
    const int* __restrict__ idx0, const int* __restrict__ idx1,
    const int* __restrict__ cnt, float* __restrict__ S, float* __restrict__ P) {
  __shared__ __align__(16) unsigned char smem[32768];
  mega_block(blockIdx.x, smem, Lb, Wh, Ws0, Ws1, Hb, logits, targets, idx0,
             idx1, cnt, S, P);
}

__global__ __launch_bounds__(256) void loss_kernel_g(
    const int* __restrict__ targets, const float* __restrict__ S,
    const float* __restrict__ P, float* __restrict__ out) {
  __shared__ __align__(16) unsigned char smem[128];
  loss_block(threadIdx.x, smem, targets, S, P, out);
}

extern "C" void kernel_launch(void* const* d_in, const int* in_sizes, int n_in,
                              void* d_out, int out_size, void* d_ws, size_t ws_size,
                              hipStream_t stream) {
  const float* logits  = (const float*)d_in[0];
  const int*   targets = (const int*)d_in[1];
  const float* head    = (const float*)d_in[2];
  const float* proj0   = (const float*)d_in[3];
  const float* scale0  = (const float*)d_in[4];
  const float* proj1   = (const float*)d_in[5];
  const float* scale1  = (const float*)d_in[6];
  float* out = (float*)d_out;
  char* ws = (char*)d_ws;

  void* args[] = {(void*)&logits, (void*)&targets, (void*)&head, (void*)&proj0,
                  (void*)&scale0, (void*)&proj1, (void*)&scale1, (void*)&ws,
                  (void*)&out};
  hipError_t err = hipLaunchCooperativeKernel(
      (const void*)uber_kernel, dim3(GRID), dim3(256), args, 0, stream);
  if (err == hipSuccess) return;

  // fallback: r5-equivalent 4-launch pipeline
  unsigned short* Hb  = (unsigned short*)(ws + B_HB);
  unsigned short* Lb  = (unsigned short*)(ws + B_LB);
  unsigned short* Wp  = (unsigned short*)(ws + B_WP);
  unsigned short* Wh  = (unsigned short*)(ws + B_WH);
  unsigned short* Ws0 = (unsigned short*)(ws + B_WS0);
  unsigned short* Ws1 = (unsigned short*)(ws + B_WS1);
  float* S = (float*)(ws + B_S);
  float* P = (float*)(ws + B_P);
  int* idx0 = (int*)(ws + B_I0);
  int* idx1 = (int*)(ws + B_I1);
  int* cnt  = (int*)(ws + B_CNT);
  prep_kernel_g<<<PP_TOTAL, 256, 0, stream>>>(head, proj0, proj1, scale0,
                                              scale1, logits, targets, Wh, Wp,
                                              Ws0, Ws1, Lb, S, idx0, idx1, cnt);
  hidden_kernel_g<<<320, 256, 0, stream>>>(Lb, Wp, Hb);
  mega_kernel_g<<<MG_TOTAL, 256, 0, stream>>>(Lb, Wh, Ws0, Ws1, Hb, logits,
                                              targets, idx0, idx1, cnt, S, P);
  loss_kernel_g<<<1, 256, 0, stream>>>(targets, S, P, out);
}

// Round 7
// 184.127 us; speedup vs baseline: 3.0294x; 3.0294x over previous
//
#include <hip/hip_runtime.h>
#include <math.h>
#include <stdint.h>

#define NROWS 4096
#define CDIM 1024
#define T0_LO 2000
#define T0_HI 10000
#define T1_LO 10000
#define ROOT_COLS 2002
#define ROOT_PAD 2048
#define T0_COLS 8000
#define T0_PAD 8064
#define T1_COLS 40257
#define T1_PAD 40320
#define HB_STRIDE 320
#define LOG2E 1.44269504088896340736f
#define LN2 0.69314718055994530942f

using short8  = __attribute__((ext_vector_type(8))) short;
using ushort8 = __attribute__((ext_vector_type(8))) unsigned short;
using floatx4 = __attribute__((ext_vector_type(4))) float;

__device__ __forceinline__ unsigned short f2bf(float x) {
  union { float f; unsigned int u; } v; v.f = x;
  unsigned int r = v.u + 0x7fffu + ((v.u >> 16) & 1u);
  return (unsigned short)(r >> 16);
}
__device__ __forceinline__ float bf2f(unsigned short h) {
  union { unsigned int u; float f; } v; v.u = ((unsigned int)h) << 16;
  return v.f;
}
__device__ __forceinline__ floatx4 mfma16(short8 a, short8 b, floatx4 c) {
  return __builtin_amdgcn_mfma_f32_16x16x32_bf16(a, b, c, 0, 0, 0);
}
// Async global->LDS 16B: lane i's data lands at lds_wave_base + i*16.
__device__ __forceinline__ void stage16(const unsigned short* g,
                                        unsigned short* lds_wave_base, int lane) {
#if __has_builtin(__builtin_amdgcn_global_load_lds)
  __builtin_amdgcn_global_load_lds(
      (const __attribute__((address_space(1))) void*)g,
      (__attribute__((address_space(3))) void*)lds_wave_base, 16, 0, 0);
#else
  ((ushort8*)lds_wave_base)[lane] = *(const ushort8*)g;
#endif
}

// ---------------- workspace layout (bytes) ----------------
static constexpr size_t B_HB  = 0;                          // ushort[4096*320]
static constexpr size_t B_LB  = B_HB + 4096ull * 320 * 2;   // ushort[4096*1024] bf16 logits
static constexpr size_t B_WP  = B_LB + 4096ull * 1024 * 2;  // ushort[384*1024] (rows 320..383 zero)
static constexpr size_t B_WH  = B_WP + 384ull * 1024 * 2;   // ushort[2048*1024]  (x log2e)
static constexpr size_t B_WS0 = B_WH + 2048ull * 1024 * 2;  // ushort[8064*256]   (x log2e, pad 64)
static constexpr size_t B_WS1 = B_WS0 + 8064ull * 256 * 2;  // ushort[40320*64]   (x log2e, pad 63)
static constexpr size_t B_S   = B_WS1 + 40320ull * 64 * 2;  // float[3*4096]
static constexpr size_t B_P   = B_S + 3ull * 4096 * 4;      // float[3*4096]
static constexpr size_t B_I0  = B_P + 3ull * 4096 * 4;
static constexpr size_t B_I1  = B_I0 + 4096ull * 4;
static constexpr size_t B_CNT = B_I1 + 4096ull * 4;

// ---------------- prep v3: 4 transpose tiles per block, reg-pipelined -------
// r21: r6's cooperative fusion failed (serial virtual-block chains, 3x).
// Prep is the ~60-85 us non-mega cost: 8989 tiny blocks each exposing full
// load latency. Now 4 tiles/block: load tile t+1 into REGISTERS before tile
// t's store phase (T14 async-stage), double-buffered LDS, 1 barrier/tile.
// Index math per mode is r5-proven; only the phasing is new.

struct TInfo {
  const float* W; unsigned short* Wt;
  int K, N, Npad, nx, rel, mode;  // mode: 0=float4, 1=float2(2 rows), 2=scalar
  float scale;
};

// transpose tile ids: Wh [0,2048) | Ws0 [2048,4064) | Ws1 [4064,6584) |
// Wp0 [6584,6840) | Wp1 [6840,6904)
__device__ __forceinline__ TInfo tp_resolve(
    int tg, const float* head, const float* scale0, const float* scale1,
    const float* proj0, const float* proj1, unsigned short* Wh,
    unsigned short* Ws0, unsigned short* Ws1, unsigned short* Wp) {
  TInfo ti;
  if (tg < 2048)      { ti.W = head;   ti.Wt = Wh;  ti.K = 1024; ti.N = ROOT_COLS; ti.Npad = ROOT_PAD; ti.nx = 64;   ti.rel = tg;        ti.mode = 1; ti.scale = LOG2E; }
  else if (tg < 4064) { ti.W = scale0; ti.Wt = Ws0; ti.K = 256;  ti.N = T0_COLS;   ti.Npad = T0_PAD;   ti.nx = 252;  ti.rel = tg - 2048; ti.mode = 0; ti.scale = LOG2E; }
  else if (tg < 6584) { ti.W = scale1; ti.Wt = Ws1; ti.K = 64;   ti.N = T1_COLS;   ti.Npad = T1_PAD;   ti.nx = 1260; ti.rel = tg - 4064; ti.mode = 2; ti.scale = LOG2E; }
  else if (tg < 6840) { ti.W = proj0;  ti.Wt = Wp;  ti.K = 1024; ti.N = 256;       ti.Npad = 256;      ti.nx = 8;    ti.rel = tg - 6584; ti.mode = 0; ti.scale = 1.f; }
  else                { ti.W = proj1;  ti.Wt = Wp + 256 * 1024; ti.K = 1024; ti.N = 64; ti.Npad = 64; ti.nx = 2; ti.rel = tg - 6840; ti.mode = 0; ti.scale = 1.f; }
  return ti;
}

__device__ __forceinline__ float4 tp_load(const TInfo& ti, int tid) {
  const int n0 = (ti.rel % ti.nx) * 32, k0 = (ti.rel / ti.nx) * 32;
  float4 v = make_float4(0.f, 0.f, 0.f, 0.f);
  if (ti.mode == 0) {          // float4: N%4==0, n%4==0 -> n+3<N <=> n<N
    const int lk = tid >> 3, ln = (tid & 7) << 2;
    const int n = n0 + ln;
    if (n + 3 < ti.N) v = *(const float4*)(ti.W + (size_t)(k0 + lk) * ti.N + n);
  } else if (ti.mode == 1) {   // float2 x rows {lk, lk+16}: N even
    const int lk = tid >> 4, ln = (tid & 15) << 1;
    const int n = n0 + ln;
    if (n + 1 < ti.N) {
      float2 a = *(const float2*)(ti.W + (size_t)(k0 + lk) * ti.N + n);
      float2 b = *(const float2*)(ti.W + (size_t)(k0 + lk + 16) * ti.N + n);
      v = make_float4(a.x, a.y, b.x, b.y);
    }
  } else {                     // scalar x rows {ty, ty+8, ty+16, ty+24}
    const int tx = tid & 31, ty = tid >> 5;
    const int n = n0 + tx;
    if (n < ti.N) {
      v.x = ti.W[(size_t)(k0 + ty) * ti.N + n];
      v.y = ti.W[(size_t)(k0 + ty + 8) * ti.N + n];
      v.z = ti.W[(size_t)(k0 + ty + 16) * ti.N + n];
      v.w = ti.W[(size_t)(k0 + ty + 24) * ti.N + n];
    }
  }
  return v;
}

__device__ __forceinline__ void tp_wlds(const TInfo& ti, int tid, float4 v,
                                        float (*tile)[33]) {
  const float s = ti.scale;
  if (ti.mode == 0) {
    const int lk = tid >> 3, ln = (tid & 7) << 2;
    tile[lk][ln] = v.x * s; tile[lk][ln + 1] = v.y * s;
    tile[lk][ln + 2] = v.z * s; tile[lk][ln + 3] = v.w * s;
  } else if (ti.mode == 1) {
    const int lk = tid >> 4, ln = (tid & 15) << 1;
    tile[lk][ln] = v.x * s; tile[lk][ln + 1] = v.y * s;
    tile[lk + 16][ln] = v.z * s; tile[lk + 16][ln + 1] = v.w * s;
  } else {
    const int tx = tid & 31, ty = tid >> 5;
    tile[ty][tx] = v.x * s; tile[ty + 8][tx] = v.y * s;
    tile[ty + 16][tx] = v.z * s; tile[ty + 24][tx] = v.w * s;
  }
}

__device__ __forceinline__ void tp_store(const TInfo& ti, int tid,
                                         float (*tile)[33]) {
  if (tid < 128) {  // 32 n-rows x 4 ushort8 (16 B) stores
    const int n0 = (ti.rel % ti.nx) * 32, k0 = (ti.rel / ti.nx) * 32;
    const int nloc = tid >> 2, kg = tid & 3;
    const int n = n0 + nloc;
    if (n < ti.Npad) {
      ushort8 x;
#pragma unroll
      for (int j = 0; j < 8; j++) x[j] = f2bf(tile[kg * 8 + j][nloc]);
      *(ushort8*)&ti.Wt[(size_t)n * ti.K + k0 + kg * 8] = x;
    }
  }
}

#define PT_NT       1726                     // 6904 transpose tiles / 4
#define PP_LB_END   (PT_NT + 2048)           // logits cast
#define PP_ZERO_END (PP_LB_END + 32)         // Wp rows 320..383
#define PP_S_END    (PP_ZERO_END + 4)        // S zero
#define PP_TOTAL    (PP_S_END + 1)           // compact (single block)

__global__ __launch_bounds__(256) void prep_kernel(
    const float* __restrict__ head, const float* __restrict__ proj0,
    const float* __restrict__ proj1, const float* __restrict__ scale0,
    const float* __restrict__ scale1, const float* __restrict__ logits,
    const int* __restrict__ targets,
    unsigned short* __restrict__ Wh, unsigned short* __restrict__ Wp,
    unsigned short* __restrict__ Ws0, unsigned short* __restrict__ Ws1,
    unsigned short* __restrict__ Lb, float* __restrict__ S,
    int* __restrict__ idx0, int* __restrict__ idx1, int* __restrict__ cnt) {
  __shared__ float bufs[2][32][33];   // 8.4 KB, double-buffered tiles
  const int id = blockIdx.x, tid = threadIdx.x;
  if (id < PT_NT) {  // 4 transpose tiles, reg-pipelined
    TInfo ti0 = tp_resolve(id * 4 + 0, head, scale0, scale1, proj0, proj1, Wh, Ws0, Ws1, Wp);
    TInfo ti1 = tp_resolve(id * 4 + 1, head, scale0, scale1, proj0, proj1, Wh, Ws0, Ws1, Wp);
    TInfo ti2 = tp_resolve(id * 4 + 2, head, scale0, scale1, proj0, proj1, Wh, Ws0, Ws1, Wp);
    TInfo ti3 = tp_resolve(id * 4 + 3, head, scale0, scale1, proj0, proj1, Wh, Ws0, Ws1, Wp);
    float4 rv = tp_load(ti0, tid);
    // t=0
    tp_wlds(ti0, tid, rv, bufs[0]);
    rv = tp_load(ti1, tid);          // latency hides under store(0)+barrier
    __syncthreads();
    tp_store(ti0, tid, bufs[0]);
    // t=1
    tp_wlds(ti1, tid, rv, bufs[1]);
    rv = tp_load(ti2, tid);
    __syncthreads();                 // also drains store(0)'s ds_reads
    tp_store(ti1, tid, bufs[1]);
    // t=2
    tp_wlds(ti2, tid, rv, bufs[0]);
    rv = tp_load(ti3, tid);
    __syncthreads();
    tp_store(ti2, tid, bufs[0]);
    // t=3
    tp_wlds(ti3, tid, rv, bufs[1]);
    __syncthreads();
    tp_store(ti3, tid, bufs[1]);
    return;
  }
  if (id < PP_LB_END) {  // logits f32 -> bf16, 2048 elements/block
    size_t base = (size_t)(id - PT_NT) * 2048 + tid * 8;
    float4 v0 = *(const float4*)(logits + base);
    float4 v1 = *(const float4*)(logits + base + 4);
    ushort8 h;
    h[0] = f2bf(v0.x); h[1] = f2bf(v0.y); h[2] = f2bf(v0.z); h[3] = f2bf(v0.w);
    h[4] = f2bf(v1.x); h[5] = f2bf(v1.y); h[6] = f2bf(v1.z); h[7] = f2bf(v1.w);
    *(ushort8*)(Lb + base) = h;
    return;
  }
  if (id < PP_ZERO_END) {  // zero Wp rows 320..383
    size_t off = (size_t)(id - PP_LB_END) * 2048 + tid * 8;
    ushort8 z = {0, 0, 0, 0, 0, 0, 0, 0};
    *(ushort8*)(Wp + 320ull * 1024 + off) = z;
    return;
  }
  if (id < PP_S_END) {  // zero S (12288 floats over 4 blocks)
    int rel = id - PP_ZERO_END;
    float4 z = make_float4(0.f, 0.f, 0.f, 0.f);
#pragma unroll
    for (int j = 0; j < 3; j++)
      ((float4*)S)[rel * 768 + j * 256 + tid] = z;
    return;
  }
  // compact: one block, LDS counters (cnt written only here)
  int* base2 = (int*)&bufs[0][0][0];
  if (tid < 2) base2[tid] = 0;
  __syncthreads();
  for (int n = tid; n < NROWS; n += 256) {
    int t = targets[n];
    if (t >= T0_LO && t < T0_HI) idx0[atomicAdd(&base2[0], 1)] = n;
    else if (t >= T1_LO)         idx1[atomicAdd(&base2[1], 1)] = n;
  }
  __syncthreads();
  if (tid < 2) cnt[tid] = base2[tid];
}

// Shared 64-row x CI-cg x K=1024 MFMA K-loop (double-buffered KC=128 halves).
template<int CI>
__device__ __forceinline__ void gemm64_kloop(
    unsigned short* A_lds,   // 2 x (64*128) ushorts = 32 KB
    const unsigned short* Arow,
    const unsigned short* const (&Bbase)[CI],
    floatx4 (&acc)[CI][4], int tid) {
  const int lane = tid & 63, w = tid >> 6;
  const int m = lane & 15, quad = lane >> 4, keym = m & 7;
  int goff[4];
#pragma unroll
  for (int it = 0; it < 4; it++) {
    int s = w * 256 + it * 64 + lane;
    int r = s >> 4, p = s & 15;
    int cq = p ^ (r & 7);
    goff[it] = r * CDIM + cq * 8;
  }
#pragma unroll
  for (int it = 0; it < 4; it++)
    stage16(Arow + goff[it], &A_lds[(w * 256 + it * 64) * 8], lane);
  for (int h = 0; h < 8; h++) {
    unsigned short* cur = A_lds + (h & 1) * (64 * 128);
    unsigned short* nxt = A_lds + ((h + 1) & 1) * (64 * 128);
    __syncthreads();
    if (h + 1 < 8) {
#pragma unroll
      for (int it = 0; it < 4; it++)
        stage16(Arow + goff[it] + (h + 1) * 128,
                &nxt[(w * 256 + it * 64) * 8], lane);
    }
    short8 b[CI][4];
#pragma unroll
    for (int ci = 0; ci < CI; ci++)
#pragma unroll
      for (int ks = 0; ks < 4; ks++)
        b[ci][ks] = *(const short8*)(Bbase[ci] + h * 128 + ks * 32);
    short8 areg[4][4];
#pragma unroll
    for (int t = 0; t < 4; t++)
#pragma unroll
      for (int ks = 0; ks < 4; ks++) {
        int ch = ((ks << 2) + quad) ^ keym;
        areg[t][ks] = *(const short8*)&cur[(t * 16 + m) * 128 + (ch << 3)];
      }
#pragma unroll
    for (int ci = 0; ci < CI; ci++)
#pragma unroll
      for (int ks = 0; ks < 4; ks++)
#pragma unroll
        for (int t = 0; t < 4; t++)
          acc[ci][t] = mfma16(areg[t][ks], b[ci][ks], acc[ci][t]);
  }
}

// ---------------- hidden: Hb[4096][320] = bf16(Lb @ Wp), 320 blocks --------
__global__ __launch_bounds__(256) void hidden_kernel(
    const unsigned short* __restrict__ Lb,
    const unsigned short* __restrict__ Wp,
    unsigned short* __restrict__ Hb) {
  __shared__ unsigned short A_lds[64 * 256];  // 2 x 16 KB halves
  const int id = blockIdx.x, tid = threadIdx.x;
  const int xcd = id & 7, k = id >> 3;          // k in [0,40)
  const int row0 = (xcd * 8 + (k & 7)) * 64;
  const int cg0 = k >> 3;                       // [0,5)
  const int lane = tid & 63, w = tid >> 6;
  const int m = lane & 15, quad = lane >> 4;
  const floatx4 zf = {0.f, 0.f, 0.f, 0.f};
  floatx4 acc[1][4];
#pragma unroll
  for (int t = 0; t < 4; t++) acc[0][t] = zf;
  const unsigned short* Bb[1] = {
      Wp + (size_t)(cg0 * 64 + w * 16 + m) * CDIM + quad * 8};
  gemm64_kloop<1>(A_lds, Lb + (size_t)row0 * CDIM, Bb, acc, tid);
  int n = cg0 * 64 + w * 16 + m;
  if (n < HB_STRIDE) {
#pragma unroll
    for (int t = 0; t < 4; t++)
#pragma unroll
      for (int r = 0; r < 4; r++)
        Hb[(size_t)(row0 + t * 16 + quad * 4 + r) * HB_STRIDE + n] =
            f2bf(acc[0][t][r]);
  }
}

// ---------------- mega kernel (r1 structure: best measured) -----------------
#define MG_ROOT 512           // 32 x-tiles (BM=128) x 16 cg-pairs
#define MG_T1   480           // 32 row-tiles (BM=128) x 15 y
#define MG_T0   2688          // 128 row-tiles x 21 y
#define MG_PICK 1024
#define MG_TOTAL (MG_ROOT + MG_T1 + MG_T0 + MG_PICK)

// Root CE, BM=128, KC=64 ping-pong double-buffer.
__device__ __forceinline__ void root_compute(
    const unsigned short* cur, const short8 (&b)[2][2], floatx4 (&acc)[2][8],
    int m, int quad, int keym) {
#pragma unroll
  for (int hf = 0; hf < 2; hf++) {
    short8 areg[4][2];
#pragma unroll
    for (int t = 0; t < 4; t++)
#pragma unroll
      for (int ks = 0; ks < 2; ks++) {
        int ch = ((ks << 2) + quad) ^ keym;
        areg[t][ks] = *(const short8*)&cur[(hf * 64 + t * 16 + m) * 64 + (ch << 3)];
      }
#pragma unroll
    for (int ci = 0; ci < 2; ci++)
#pragma unroll
      for (int ks = 0; ks < 2; ks++)
#pragma unroll
        for (int t = 0; t < 4; t++)
          acc[ci][hf * 4 + t] = mfma16(areg[t][ks], b[ci][ks], acc[ci][hf * 4 + t]);
  }
}

__device__ __forceinline__ void root_stage(
    const unsigned short* Arow, const int (&goff)[4], int koff,
    unsigned short* buf, int w, int lane) {
#pragma unroll
  for (int it = 0; it < 4; it++)
    stage16(Arow + goff[it] + koff, &buf[(it * 256 + w * 64) * 8], lane);
}

__device__ __forceinline__ void root_loadB(
    const unsigned short* const (&Bb)[2], int koff, short8 (&b)[2][2]) {
#pragma unroll
  for (int ci = 0; ci < 2; ci++)
#pragma unroll
    for (int ks = 0; ks < 2; ks++)
      b[ci][ks] = *(const short8*)(Bb[ci] + koff + ks * 32);
}

__device__ __forceinline__ void root_path(
    unsigned char* smem, int bx, int by,
    const unsigned short* __restrict__ Lb,
    const unsigned short* __restrict__ Wh, float* __restrict__ S) {
  unsigned short* bufA = (unsigned short*)smem;   // 128 rows x 64 k = 16 KB
  unsigned short* bufB = bufA + 128 * 64;         // second half
  const int tid = threadIdx.x;
  const int row0 = bx * 128;
  const int cg0 = by * 2;
  const int lane = tid & 63, w = tid >> 6;
  const int m = lane & 15, quad = lane >> 4, keym = m & 7;
  const floatx4 zf = {0.f, 0.f, 0.f, 0.f};
  floatx4 acc[2][8];
#pragma unroll
  for (int ci = 0; ci < 2; ci++)
#pragma unroll
    for (int t = 0; t < 8; t++) acc[ci][t] = zf;
  const unsigned short* Bb[2] = {
      Wh + (size_t)((cg0 + 0) * 64 + w * 16 + m) * CDIM + quad * 8,
      Wh + (size_t)((cg0 + 1) * 64 + w * 16 + m) * CDIM + quad * 8};
  const unsigned short* Arow = Lb + (size_t)row0 * CDIM;
  int goff[4];
#pragma unroll
  for (int it = 0; it < 4; it++) {
    int s = it * 256 + w * 64 + lane;
    int r = s >> 3, p = s & 7;
    int cq = p ^ (r & 7);
    goff[it] = r * CDIM + cq * 8;
  }
  short8 b0[2][2], b1[2][2];
  root_stage(Arow, goff, 0, bufA, w, lane);   // chunk 0 in flight
  root_loadB(Bb, 0, b0);
  for (int hh = 0; hh < 8; hh++) {
    __syncthreads();                          // drains chunk 2hh into bufA
    root_stage(Arow, goff, (hh * 2 + 1) * 64, bufB, w, lane);
    root_loadB(Bb, (hh * 2 + 1) * 64, b1);
    root_compute(bufA, b0, acc, m, quad, keym);
    __syncthreads();                          // drains chunk 2hh+1 into bufB
    if (hh < 7) {
      root_stage(Arow, goff, (hh * 2 + 2) * 64, bufA, w, lane);
      root_loadB(Bb, (hh * 2 + 2) * 64, b0);
    }
    root_compute(bufB, b1, acc, m, quad, keym);
  }
  // epilogue: reuse smem for 128 per-row sums
  __syncthreads();
  float* sums = (float*)smem;
  if (tid < 128) sums[tid] = 0.f;
  __syncthreads();
#pragma unroll
  for (int t = 0; t < 8; t++)
#pragma unroll
    for (int r = 0; r < 4; r++) {
      float e = __builtin_amdgcn_exp2f(acc[0][t][r]) +
                __builtin_amdgcn_exp2f(acc[1][t][r]);
      e += __shfl_xor(e, 1); e += __shfl_xor(e, 2);
      e += __shfl_xor(e, 4); e += __shfl_xor(e, 8);
      if (m == 0)
        atomicAdd(&sums[(t >> 2) * 64 + (t & 3) * 16 + quad * 4 + r], e);
    }
  __syncthreads();
  if (tid < 128) atomicAdd(&S[row0 + tid], sums[tid]);
}

// Tail CE path: A in regs, runtime cg loop, 2 cgs/iter through literally-
// indexed b0/b1 with 2-deep prefetch.
template<int K, int TILES, int MODE>
__device__ __forceinline__ void tail_path(
    unsigned char* smem, int bx, int by,
    const unsigned short* __restrict__ Hb, int acol0,
    const unsigned short* __restrict__ Wt, int ncgpb,
    const int* __restrict__ idx, const int* __restrict__ cnt,
    float* __restrict__ S) {
  constexpr int BM = TILES * 16;
  constexpr int CpR = K / 8;
  constexpr int KS = K / 32;
  unsigned short* A_lds = (unsigned short*)smem;            // BM*K ushorts
  int* row_lds = (int*)(smem + (size_t)BM * K * 2);
  float* sum_lds = (float*)(smem + (size_t)BM * K * 2 + BM * 4);
  const int tid = threadIdx.x;
  const int count = cnt[MODE - 1];
  const int row0 = bx * BM;
  if (row0 >= count) return;
  if (tid < BM) {
    int r = row0 + tid;
    row_lds[tid] = (r < count) ? idx[r] : -1;
    sum_lds[tid] = 0.f;
  }
  __syncthreads();
#pragma unroll
  for (int i = 0; i < BM * CpR / 256; i++) {
    int c = tid + 256 * i;
    int rl = c / CpR, cq = c % CpR;
    int row = row_lds[rl];
    ushort8 v = {0, 0, 0, 0, 0, 0, 0, 0};
    if (row >= 0) v = *(const ushort8*)(Hb + (size_t)row * HB_STRIDE + acol0 + cq * 8);
    *(ushort8*)&A_lds[rl * K + ((cq ^ (rl & 7)) << 3)] = v;
  }
  __syncthreads();
  const int lane = tid & 63, w = tid >> 6;
  const int m = lane & 15, quad = lane >> 4, keym = m & 7;
  const floatx4 zf = {0.f, 0.f, 0.f, 0.f};
  short8 areg[TILES][KS];
#pragma unroll
  for (int t = 0; t < TILES; t++)
#pragma unroll
    for (int ks = 0; ks < KS; ks++) {
      int ch = ((ks << 2) + quad) ^ keym;
      areg[t][ks] = *(const short8*)&A_lds[(t * 16 + m) * K + (ch << 3)];
    }
  float runsum[TILES][4];
#pragma unroll
  for (int t = 0; t < TILES; t++)
#pragma unroll
    for (int r = 0; r < 4; r++) runsum[t][r] = 0.f;

  const int cg0 = by * ncgpb;
  const unsigned short* Bp = Wt + (size_t)(cg0 * 64 + w * 16 + m) * K + quad * 8;
  short8 b0[KS], b1[KS];
#pragma unroll
  for (int ks = 0; ks < KS; ks++) b0[ks] = *(const short8*)(Bp + ks * 32);
#pragma unroll
  for (int ks = 0; ks < KS; ks++)
    b1[ks] = *(const short8*)(Bp + (size_t)64 * K + ks * 32);

  for (int cc = 0; cc < ncgpb; cc += 2) {  // runtime loop, literal reg indices
    floatx4 acc[TILES];
#pragma unroll
    for (int t = 0; t < TILES; t++) acc[t] = zf;
#pragma unroll
    for (int ks = 0; ks < KS; ks++)
#pragma unroll
      for (int t = 0; t < TILES; t++) acc[t] = mfma16(areg[t][ks], b0[ks], acc[t]);
    if (cc + 2 < ncgpb) {
      const unsigned short* p = Bp + (size_t)(cc + 2) * 64 * K;
#pragma unroll
      for (int ks = 0; ks < KS; ks++) b0[ks] = *(const short8*)(p + ks * 32);
    }
#pragma unroll
    for (int t = 0; t < TILES; t++)
#pragma unroll
      for (int r = 0; r < 4; r++)
        runsum[t][r] += __builtin_amdgcn_exp2f(acc[t][r]);

#pragma unroll
    for (int t = 0; t < TILES; t++) acc[t] = zf;
#pragma unroll
    for (int ks = 0; ks < KS; ks++)
#pragma unroll
      for (int t = 0; t < TILES; t++) acc[t] = mfma16(areg[t][ks], b1[ks], acc[t]);
    if (cc + 3 < ncgpb) {
      const unsigned short* p = Bp + (size_t)(cc + 3) * 64 * K;
#pragma unroll
      for (int ks = 0; ks < KS; ks++) b1[ks] = *(const short8*)(p + ks * 32);
    }
#pragma unroll
    for (int t = 0; t < TILES; t++)
#pragma unroll
      for (int r = 0; r < 4; r++)
        runsum[t][r] += __builtin_amdgcn_exp2f(acc[t][r]);
  }

#pragma unroll
  for (int t = 0; t < TILES; t++)
#pragma unroll
    for (int r = 0; r < 4; r++) {
      float e = runsum[t][r];
      e += __shfl_xor(e, 1); e += __shfl_xor(e, 2);
      e += __shfl_xor(e, 4); e += __shfl_xor(e, 8);
      if (m == 0) atomicAdd(&sum_lds[t * 16 + quad * 4 + r], e);
    }
  __syncthreads();
  if (tid < BM) {
    int row = row_lds[tid];
    if (row >= 0) atomicAdd(&S[row], sum_lds[tid]);
  }
}

__device__ __forceinline__ void picked_path(
    int rel, const float* __restrict__ logits, const int* __restrict__ targets,
    const unsigned short* __restrict__ Wh,
    const unsigned short* __restrict__ Ws0,
    const unsigned short* __restrict__ Ws1,
    const unsigned short* __restrict__ Hb, float* __restrict__ P) {
  const int tid = threadIdx.x, lane = tid & 63;
  const int row = rel * 4 + (tid >> 6);
  const int t = targets[row];
  const int tr = (t >= T0_LO && t < T0_HI) ? T0_LO : ((t >= T1_LO) ? T0_LO + 1 : t);
  const float* a = logits + (size_t)row * CDIM + lane * 16;
  const unsigned short* wr = Wh + (size_t)tr * CDIM + lane * 16;
  float acc = 0.f;
#pragma unroll
  for (int q = 0; q < 2; q++) {
    ushort8 wv = *(const ushort8*)(wr + q * 8);
    float4 a0 = ((const float4*)a)[q * 2];
    float4 a1 = ((const float4*)a)[q * 2 + 1];
    acc += a0.x * bf2f(wv[0]) + a0.y * bf2f(wv[1]) + a0.z * bf2f(wv[2]) + a0.w * bf2f(wv[3]);
    acc += a1.x * bf2f(wv[4]) + a1.y * bf2f(wv[5]) + a1.z * bf2f(wv[6]) + a1.w * bf2f(wv[7]);
  }
#pragma unroll
  for (int off = 1; off < 64; off <<= 1) acc += __shfl_xor(acc, off);
  if (lane == 0) P[row] = acc * LN2;
  if (t >= T0_LO) {
    float acc2 = 0.f;
    if (t < T0_HI) {
      const unsigned short* h = Hb + (size_t)row * HB_STRIDE + lane * 4;
      const unsigned short* w2 = Ws0 + (size_t)(t - T0_LO) * 256 + lane * 4;
#pragma unroll
      for (int j = 0; j < 4; j++) acc2 += bf2f(h[j]) * bf2f(w2[j]);
    } else {
      acc2 = bf2f(Hb[(size_t)row * HB_STRIDE + 256 + lane]) *
             bf2f(Ws1[(size_t)(t - T1_LO) * 64 + lane]);
    }
#pragma unroll
    for (int off = 1; off < 64; off <<= 1) acc2 += __shfl_xor(acc2, off);
    if (lane == 0) P[(t < T0_HI ? NROWS : 2 * NROWS) + row] = acc2 * LN2;
  }
}

__global__ __launch_bounds__(256, 2) void mega_kernel(
    const unsigned short* __restrict__ Lb,
    const unsigned short* __restrict__ Wh,
    const unsigned short* __restrict__ Ws0,
    const unsigned short* __restrict__ Ws1,
    const unsigned short* __restrict__ Hb,
    const float* __restrict__ logits, const int* __restrict__ targets,
    const int* __restrict__ idx0, const int* __restrict__ idx1,
    const int* __restrict__ cnt, float* __restrict__ S, float* __restrict__ P) {
  __shared__ __align__(16) unsigned char smem[32768];
  int bid = blockIdx.x;
  if (bid < MG_ROOT) {
    // XCD remap: each XCD owns a contiguous 64-block chunk, y-fastest.
    int wk = ((bid & 7) << 6) + (bid >> 3);      // [0,512) bijective
    root_path(smem, wk >> 4, wk & 15, Lb, Wh, S);
    return;
  }
  bid -= MG_ROOT;
  if (bid < MG_T1) {
    int wk = (bid & 7) * 60 + (bid >> 3);        // [0,480) bijective
    tail_path<64, 8, 2>(smem, wk & 31, wk >> 5, Hb, 256, Ws1, 42, idx1, cnt,
                        S + 2 * NROWS);
    return;
  }
  bid -= MG_T1;
  if (bid < MG_T0) {
    int wk = (bid & 7) * 336 + (bid >> 3);       // [0,2688) bijective
    tail_path<256, 2, 1>(smem, wk & 127, wk >> 7, Hb, 0, Ws0, 6, idx0, cnt,
                         S + NROWS);
    return;
  }
  bid -= MG_T0;
  picked_path(bid, logits, targets, Wh, Ws0, Ws1, Hb, P);
}

__global__ __launch_bounds__(1024) void loss_kernel(
    const int* __restrict__ targets,
    const float* __restrict__ S,   // [3][NROWS]
    const float* __restrict__ P,   // [3][NROWS]
    float* __restrict__ out) {
  const int tid = threadIdx.x;
  float sr = 0.f, s0 = 0.f, s1 = 0.f, c0 = 0.f, c1 = 0.f;
  for (int n = tid; n < NROWS; n += 1024) {
    int t = targets[n];
    sr += logf(S[n] - 46.f) - P[n];  // 46 root pad cols -> exp2(0)=1 each
    if (t >= T0_LO && t < T0_HI) { s0 += logf(S[NROWS + n] - 64.f) - P[NROWS + n]; c0 += 1.f; }
    else if (t >= T1_LO)         { s1 += logf(S[2 * NROWS + n] - 63.f) - P[2 * NROWS + n]; c1 += 1.f; }
  }
  for (int off = 32; off > 0; off >>= 1) {
    sr += __shfl_down(sr, off);
    s0 += __shfl_down(s0, off);
    s1 += __shfl_down(s1, off);
    c0 += __shfl_down(c0, off);
    c1 += __shfl_down(c1, off);
  }
  __shared__ float red[16][5];
  int wv = tid >> 6;
  if ((tid & 63) == 0) { red[wv][0] = sr; red[wv][1] = s0; red[wv][2] = s1; red[wv][3] = c0; red[wv][4] = c1; }
  __syncthreads();
  if (tid == 0) {
    sr = 0.f; s0 = 0.f; s1 = 0.f; c0 = 0.f; c1 = 0.f;
#pragma unroll
    for (int i = 0; i < 16; i++) {
      sr += red[i][0]; s0 += red[i][1]; s1 += red[i][2];
      c0 += red[i][3]; c1 += red[i][4];
    }
    float root_loss = sr / (float)NROWS;
    float l0 = s0 / fmaxf(c0, 1.f);
    float l1 = s1 / fmaxf(c1, 1.f);
    out[0] = (root_loss + l0 + l1) / 3.f;
  }
}

extern "C" void kernel_launch(void* const* d_in, const int* in_sizes, int n_in,
                              void* d_out, int out_size, void* d_ws, size_t ws_size,
                              hipStream_t stream) {
  const float* logits  = (const float*)d_in[0];
  const int*   targets = (const int*)d_in[1];
  const float* head    = (const float*)d_in[2];
  const float* proj0   = (const float*)d_in[3];
  const float* scale0  = (const float*)d_in[4];
  const float* proj1   = (const float*)d_in[5];
  const float* scale1  = (const float*)d_in[6];
  float* out = (float*)d_out;
  char* ws = (char*)d_ws;

  unsigned short* Hb  = (unsigned short*)(ws + B_HB);
  unsigned short* Lb  = (unsigned short*)(ws + B_LB);
  unsigned short* Wp  = (unsigned short*)(ws + B_WP);
  unsigned short* Wh  = (unsigned short*)(ws + B_WH);
  unsigned short* Ws0 = (unsigned short*)(ws + B_WS0);
  unsigned short* Ws1 = (unsigned short*)(ws + B_WS1);
  float* S = (float*)(ws + B_S);
  float* P = (float*)(ws + B_P);
  int* idx0 = (int*)(ws + B_I0);
  int* idx1 = (int*)(ws + B_I1);
  int* cnt  = (int*)(ws + B_CNT);

  prep_kernel<<<PP_TOTAL, 256, 0, stream>>>(head, proj0, proj1, scale0, scale1,
                                            logits, targets, Wh, Wp, Ws0, Ws1,
                                            Lb, S, idx0, idx1, cnt);
  hidden_kernel<<<320, 256, 0, stream>>>(Lb, Wp, Hb);
  mega_kernel<<<MG_TOTAL, 256, 0, stream>>>(Lb, Wh, Ws0, Ws1, Hb, logits,
                                            targets, idx0, idx1, cnt, S, P);
  loss_kernel<<<1, 1024, 0, stream>>>(targets, S, P, out);
}